// Round 6
// baseline (115.172 us; speedup 1.0000x reference)
//
#include <hip/hip_runtime.h>

#define GQ   8192            // bs(32) * Gn(256)
#define WPB  2               // waves per block
#define GPW  2               // groups per wave (g, g+1 share 128B feature lines)
#define MROW 132             // M row stride in floats
#define SLICE 1280           // per-wave LDS floats: M 9x132 + SIMM 81 + pad

// Wave-local LDS fence: all LDS use is wave-private, no block barrier needed.
#define LDS_FENCE() asm volatile("s_waitcnt lgkmcnt(0)" ::: "memory")
#define COMP(v4, k) ((k)==0?(v4).x:((k)==1?(v4).y:((k)==2?(v4).z:(v4).w)))

// One wave processes 2 consecutive groups; BOTH groups' features prefetched at
// wave start (16 KB in flight) so group-1's HBM latency is fully hidden behind
// group-0's compute. No __syncthreads anywhere: waves are independent.
__global__ __launch_bounds__(64 * WPB, 4) void group_loss_kernel(
    const int*   __restrict__ labs,   // [G*16]
    const float* __restrict__ feats,  // [32,128,256,16]
    const int*   __restrict__ idxs,   // [G*16]
    const float* __restrict__ ctx,    // [128]
    float2* __restrict__ ws)          // [G] {gl*gv, gv}
{
    __shared__ float SH[WPB * SLICE];          // 10.2 KB/block

    const int l  = threadIdx.x & 63;
    const int wu = threadIdx.x >> 6;
    float* MM   = SH + wu * SLICE;             // 9 x 132 (wave-private)
    float* SIMM = MM + 9 * MROW;               // 81

    const int blk = blockIdx.x;
    // XCD blk&7 owns groups [x<<10,(x+1)<<10); block covers 4 consecutive gn
    const int gbase = ((blk & 7) << 10) | ((blk >> 3) << 2) | (wu << 1);
    const int b  = gbase >> 8;                 // g,g+1 never cross a b boundary
    const int gn = gbase & 255;
    const long fbase = (long)b * (128 * 256 * 16) + (long)gn * 16;

    // ---- prefetch BOTH groups' feature columns (lane l -> channels l, l+64)
    const float* gp = feats + fbase + (long)l * 4096;
    float4 A[2][4], B[2][4];
    #pragma unroll
    for (int q = 0; q < 4; ++q) {
        A[0][q] = *(const float4*)(gp + q * 4);              // g0, chan l
        A[1][q] = *(const float4*)(gp + 16 + q * 4);         // g1 (same line)
        B[0][q] = *(const float4*)(gp + 64 * 4096 + q * 4);  // g0, chan l+64
        B[1][q] = *(const float4*)(gp + 64 * 4096 + 16 + q * 4);
    }
    // labels/indices for both groups in one 32-lane load
    int raw_idx = 0, raw_lab = -2;
    if (l < 32) { raw_idx = idxs[gbase * 16 + l]; raw_lab = labs[gbase * 16 + l]; }
    const float cx0 = ctx[l], cx1 = ctx[l + 64];

    #pragma unroll
    for (int t = 0; t < GPW; ++t) {
        const int g = gbase + t;

        // realign: lane l gets sample (l&15) of group t
        const int myidx = __shfl(raw_idx, (l & 15) + 16 * t);
        const int mylab = __shfl(raw_lab, (l & 15) + 16 * t);

        // u = count of distinct seed indices (first-occurrence positions)
        bool dup = false;
        #pragma unroll
        for (int j = 0; j < 15; ++j) {
            const int vj = __shfl(myidx, j);
            dup = dup || ((l > j) && (myidx == vj));
        }
        const int u = __popcll(__ballot((l < 16) && !dup));

        const bool valid = l < u;               // u<=16 -> lanes>=16 invalid
        const int bid = valid ? (mylab + 1) : 255;

        int cnt[9];
        #pragma unroll
        for (int r = 0; r < 9; ++r) cnt[r] = __popcll(__ballot(bid == r));
        const bool has_bg = cnt[0] > 0;
        int fg_count = 0, pm = 0;
        #pragma unroll
        for (int r = 1; r < 9; ++r)
            if (cnt[r] > 0) { ++fg_count; pm |= 1 << r; }

        // bucket sums: 16 uniform dispatches (readlane -> scalar switch)
        float m0[9] = {0,0,0,0,0,0,0,0,0};
        float m1[9] = {0,0,0,0,0,0,0,0,0};
        #pragma unroll
        for (int s = 0; s < 16; ++s) {
            if (s < u) {
                const int bs = __builtin_amdgcn_readlane(bid, s);
                const float fas = COMP(A[t][s >> 2], s & 3);
                const float fbs = COMP(B[t][s >> 2], s & 3);
                switch (bs) {
                    case 0: m0[0] += fas; m1[0] += fbs; break;
                    case 1: m0[1] += fas; m1[1] += fbs; break;
                    case 2: m0[2] += fas; m1[2] += fbs; break;
                    case 3: m0[3] += fas; m1[3] += fbs; break;
                    case 4: m0[4] += fas; m1[4] += fbs; break;
                    case 5: m0[5] += fas; m1[5] += fbs; break;
                    case 6: m0[6] += fas; m1[6] += fbs; break;
                    case 7: m0[7] += fas; m1[7] += fbs; break;
                    case 8: m0[8] += fas; m1[8] += fbs; break;
                }
            }
        }
        #pragma unroll
        for (int r = 0; r < 9; ++r) {
            const float invc = 1.0f / (float)(cnt[r] > 0 ? cnt[r] : 1);
            m0[r] *= invc; m1[r] *= invc;
        }
        if (!has_bg) { m0[0] = cx0; m1[0] = cx1; }

        // M -> wave-private LDS (WAR fence vs previous iteration's reads)
        LDS_FENCE();
        #pragma unroll
        for (int r = 0; r < 9; ++r) {
            MM[r * MROW + l]      = m0[r];
            MM[r * MROW + 64 + l] = m1[r];
        }
        LDS_FENCE();

        // 44 pairs (i,j), 1<=i<=8, 0<=j<=i: lane p dots rows i,j (4 acc chains)
        float simv = 0.0f; int pi = 0, pj = 0;
        if (l < 44) {
            pi = (int)((sqrtf(8.0f * (float)l + 9.0f) - 1.0f) * 0.5f);
            pj = l - (pi * (pi + 1) / 2 - 1);
            const float* Ri = MM + pi * MROW;
            const float* Rj = MM + pj * MROW;
            float ax = 0.f, ay = 0.f, az = 0.f, aw = 0.f;
            #pragma unroll
            for (int q = 0; q < 32; ++q) {
                float4 x = *(const float4*)(Ri + 4 * q);
                float4 y = *(const float4*)(Rj + 4 * q);
                ax += x.x * y.x; ay += x.y * y.y;
                az += x.z * y.z; aw += x.w * y.w;
            }
            simv = ((ax + ay) + (az + aw)) * 5.0f;   // 1/T
        }
        if (l < 44) {
            SIMM[pi * 9 + pj] = simv;
            if (pi != pj) SIMM[pj * 9 + pi] = simv;
        }
        LDS_FENCE();

        // masked logsumexp per present fg row (lane r = row r)
        float li_val = 0.0f;
        if (l >= 1 && l < 9 && ((pm >> l) & 1)) {
            float srow[9];
            #pragma unroll
            for (int j = 0; j < 9; ++j) srow[j] = SIMM[l * 9 + j];
            float vmax = srow[0];               // col 0 (bg/ctx) always valid
            #pragma unroll
            for (int j = 1; j < 9; ++j)
                if ((pm >> j) & 1) vmax = fmaxf(vmax, srow[j]);
            float se = __expf(srow[0] - vmax);
            #pragma unroll
            for (int j = 1; j < 9; ++j)
                if ((pm >> j) & 1) se += __expf(srow[j] - vmax);
            li_val = vmax + __logf(se) - srow[l];
        }

        // sum li over lanes 1..8; single float2 store
        float ssum = li_val;
        #pragma unroll
        for (int off = 8; off >= 1; off >>= 1) ssum += __shfl_down(ssum, off);
        if (l == 0) {
            float2 r;
            r.x = ssum / (float)(fg_count > 0 ? fg_count : 1);  // gl*gv
            r.y = (fg_count > 0) ? 1.0f : 0.0f;                 // gv
            ws[g] = r;
        }
    }
}

// Deterministic 8192 -> 1 reduction
__global__ __launch_bounds__(1024) void reduce_kernel(
    const float2* __restrict__ ws, float* __restrict__ out)
{
    __shared__ float sa[1024], sb[1024];
    const int t = threadIdx.x;
    float a = 0.0f, b2 = 0.0f;
    for (int g = t; g < GQ; g += 1024) {
        float2 v = ws[g];
        a += v.x; b2 += v.y;
    }
    sa[t] = a; sb[t] = b2;
    __syncthreads();
    for (int off = 512; off > 0; off >>= 1) {
        if (t < off) { sa[t] += sa[t + off]; sb[t] += sb[t + off]; }
        __syncthreads();
    }
    if (t == 0) out[0] = 0.1f * (sa[0] / sb[0]);
}

extern "C" void kernel_launch(void* const* d_in, const int* in_sizes, int n_in,
                              void* d_out, int out_size, void* d_ws, size_t ws_size,
                              hipStream_t stream) {
    const int*   labs  = (const int*)d_in[0];    // proposal_instance_mask
    const float* feats = (const float*)d_in[1];  // grouped_features
    const int*   idxs  = (const int*)d_in[2];    // grouped_indices
    const float* ctx   = (const float*)d_in[3];  // context_compen
    float* out = (float*)d_out;
    float2* ws = (float2*)d_ws;

    group_loss_kernel<<<GQ / (WPB * GPW), 64 * WPB, 0, stream>>>(labs, feats, idxs, ctx, ws);
    reduce_kernel<<<1, 1024, 0, stream>>>(ws, out);
}